// Round 2
// baseline (114.642 us; speedup 1.0000x reference)
//
#include <hip/hip_runtime.h>

#define GS   7
#define CCH  490
#define HH   128
#define WW   128
#define LDW  132        // padded LDS row stride (floats): row start = 528 B, 16B-aligned
                        // -> conflict-free b128 row access (phase B) and free b32/b64 col access
#define NB   2

typedef float v2f __attribute__((ext_vector_type(2)));

__global__ __launch_bounds__(512, 4) void psroi_fused(
    const float* __restrict__ rois,
    const float* __restrict__ feat,
    const int*   __restrict__ stride_p,
    float*       __restrict__ out)
{
#pragma clang fp contract(off)
    __shared__ float S[HH * LDW];   // 67,584 B -> 2 blocks/CU

    const int bc = blockIdx.x;
    const int b  = bc / CCH;
    const int c  = bc - b * CCH;
    const float* __restrict__ f = feat + (size_t)bc * (HH * WW);
    const int tid = threadIdx.x;

    // ---- Phase A: cumsum over H. thread = (col-pair, 16-row seg); seg == wave id.
    // dwordx2 loads: 512 B per wave-instr (2x round-0), 16 instrs instead of 32.
    {
        const int c2 = tid & 63;        // column pair: cols {2*c2, 2*c2+1}
        const int sg = tid >> 6;        // 0..7 == wave id -> uniform branches
        const int r0 = sg * 16;

        v2f v[16];
        const v2f* fp = (const v2f*)(f + r0 * WW) + c2;
        #pragma unroll
        for (int i = 0; i < 16; ++i)    // streamed, read-once: nontemporal
            v[i] = __builtin_nontemporal_load(&fp[i * (WW / 2)]);
        #pragma unroll
        for (int i = 1; i < 16; ++i)    // two independent 15-chains (one per column)
            v[i] += v[i - 1];

        // seg-total exchange through S rows 0..7 (overwritten by seg-0 final writes later)
        *(v2f*)&S[sg * LDW + 2 * c2] = v[15];
        __syncthreads();
        v2f off = {0.0f, 0.0f};         // sg uniform per wave -> uniform branches
        #pragma unroll
        for (int s = 0; s < 7; ++s)
            if (sg > s) off += *(const v2f*)&S[s * LDW + 2 * c2];
        __syncthreads();                // offset reads done before overwrites

        float* sp = &S[r0 * LDW + 2 * c2];
        #pragma unroll
        for (int i = 0; i < 16; ++i) {  // 16x ds_write_b64, imm offsets
            v2f q = v[i] + off;
            *(v2f*)&sp[i * LDW] = q;
        }
    }
    __syncthreads();

    // ---- Phase B: cumsum over W. thread = (row, 32-col seg); quads share a row.
    {
        const int row = tid >> 2;       // wave = 16 rows x 4 col-segs
        const int ws_ = tid & 3;
        float* rp = &S[row * LDW + ws_ * 32];

        float u[32];
        #pragma unroll
        for (int i = 0; i < 8; ++i) {   // 8x ds_read_b128, imm offsets, conflict-free
            const float4 q = *(const float4*)&rp[i * 4];
            u[4 * i + 0] = q.x; u[4 * i + 1] = q.y;
            u[4 * i + 2] = q.z; u[4 * i + 3] = q.w;
        }
        #pragma unroll
        for (int i = 1; i < 32; ++i)
            u[i] += u[i - 1];

        const float tot = u[31];        // cross-seg fixup: 3 shuffles within quad
        const float t1 = __shfl_up(tot, 1, 64);
        const float t2 = __shfl_up(tot, 2, 64);
        const float t3 = __shfl_up(tot, 3, 64);
        float off = 0.0f;
        if (ws_ > 0) off += t1;
        if (ws_ > 1) off += t2;
        if (ws_ > 2) off += t3;

        #pragma unroll
        for (int i = 0; i < 8; ++i) {   // 8x ds_write_b128 in place
            float4 q;
            q.x = u[4 * i + 0] + off; q.y = u[4 * i + 1] + off;
            q.z = u[4 * i + 2] + off; q.w = u[4 * i + 3] + off;
            *(float4*)&rp[i * 4] = q;
        }
    }
    __syncthreads();

    // ---- Phase 3: pooling — thread n handles roi n for this channel ----
    {
        const int n = tid;              // 512 threads == 512 rois
        const float b_f = rois[n * 5 + 0];
        const int bi = (int)b_f;
        if (bi == b) {
            const float ss = 1.0f / (float)(*stride_p);
            const int d   = c / (GS * GS);
            const int rem = c - d * (GS * GS);
            const int pi  = rem / GS;
            const int pj  = rem - pi * GS;

            const float x1 = rois[n * 5 + 1];
            const float y1 = rois[n * 5 + 2];
            const float x2 = rois[n * 5 + 3];
            const float y2 = rois[n * 5 + 4];

            // exact reference op order, fp32, no contraction
            float rsw = rintf(x1) * ss;
            float rsh = rintf(y1) * ss;
            float rew = (rintf(x2) + 1.0f) * ss;
            float reh = (rintf(y2) + 1.0f) * ss;
            float rwv = rew - rsw;
            float rhv = reh - rsh;
            float rwm = rwv * 1.3f;
            float rhm = rhv * 1.3f;
            float swm = (rsw + rew) * 0.5f - rwm * 0.5f;
            float shm = (rsh + reh) * 0.5f - rhm * 0.5f;
            rwm = fmaxf(rwm, 0.1f);
            rhm = fmaxf(rhm, 0.1f);
            float bin_h = rhm / 7.0f;
            float bin_w = rwm / 7.0f;
            float dh = bin_h * 0.25f;
            float dw = bin_w * 0.25f;

            const float gi = (float)pi;
            const float gj = (float)pj;
            const int hs  = (int)fminf(fmaxf(floorf(shm + gi * bin_h - dh),          0.0f), 128.0f);
            const int he  = (int)fminf(fmaxf(ceilf (shm + (gi + 1.0f) * bin_h + dh), 0.0f), 128.0f);
            const int ws2 = (int)fminf(fmaxf(floorf(swm + gj * bin_w - dw),          0.0f), 128.0f);
            const int we  = (int)fminf(fmaxf(ceilf (swm + (gj + 1.0f) * bin_w + dw), 0.0f), 128.0f);

            const int area = (he - hs) * (we - ws2);
            const float A  = (he > 0 && we  > 0) ? S[(he - 1) * LDW + (we  - 1)] : 0.0f;
            const float Bv = (hs > 0 && we  > 0) ? S[(hs - 1) * LDW + (we  - 1)] : 0.0f;
            const float Cv = (he > 0 && ws2 > 0) ? S[(he - 1) * LDW + (ws2 - 1)] : 0.0f;
            const float Dv = (hs > 0 && ws2 > 0) ? S[(hs - 1) * LDW + (ws2 - 1)] : 0.0f;
            const float total = ((A - Bv) - Cv) + Dv;   // reference order
            const float res = (area > 0) ? (total / (float)area) : 0.0f;
            __builtin_nontemporal_store(res, &out[(size_t)n * CCH + c]);  // write-once, scattered
        }
    }
}

extern "C" void kernel_launch(void* const* d_in, const int* in_sizes, int n_in,
                              void* d_out, int out_size, void* d_ws, size_t ws_size,
                              hipStream_t stream)
{
    const float* rois     = (const float*)d_in[0];
    const float* feat     = (const float*)d_in[1];
    const int*   stride_p = (const int*)d_in[2];
    float*       out      = (float*)d_out;

    dim3 grid(NB * CCH);   // one workgroup per (batch, channel)
    dim3 block(512);
    hipLaunchKernelGGL(psroi_fused, grid, block, 0, stream, rois, feat, stride_p, out);
}

// Round 3
// 98.974 us; speedup vs baseline: 1.1583x; 1.1583x over previous
//
#include <hip/hip_runtime.h>

#define GS   7
#define CCH  490
#define HH   128
#define WW   128
#define LDW  132        // padded LDS row stride (floats): row start = 528 B, 16B-aligned
                        // -> conflict-free b128 row access (phase B) and free b32/b64 col access
#define NB   2

typedef float v2f __attribute__((ext_vector_type(2)));

__global__ __launch_bounds__(512, 4) void psroi_fused(
    const float* __restrict__ rois,
    const float* __restrict__ feat,
    const int*   __restrict__ stride_p,
    float*       __restrict__ out)
{
#pragma clang fp contract(off)
    __shared__ float S[HH * LDW];   // 67,584 B -> 2 blocks/CU

    const int bc = blockIdx.x;
    const int b  = bc / CCH;
    const int c  = bc - b * CCH;
    const float* __restrict__ f = feat + (size_t)bc * (HH * WW);
    const int tid = threadIdx.x;

    // ---- Phase A: cumsum over H. thread = (col-pair, 16-row seg); seg == wave id.
    // dwordx2 loads: 512 B per wave-instr, 16 instrs. NO nontemporal: features are
    // L3-resident (restored by the harness each iteration) — NT hints doubled kernel
    // time in round 2 by forcing HBM reads.
    {
        const int c2 = tid & 63;        // column pair: cols {2*c2, 2*c2+1}
        const int sg = tid >> 6;        // 0..7 == wave id -> uniform branches
        const int r0 = sg * 16;

        v2f v[16];
        const v2f* fp = (const v2f*)(f + r0 * WW) + c2;
        #pragma unroll
        for (int i = 0; i < 16; ++i)    // coalesced: 512B per wave-load, L3-fed
            v[i] = fp[i * (WW / 2)];
        #pragma unroll
        for (int i = 1; i < 16; ++i)    // two independent 15-chains (one per column)
            v[i] += v[i - 1];

        // seg-total exchange through S rows 0..7 (overwritten by final writes later)
        *(v2f*)&S[sg * LDW + 2 * c2] = v[15];
        __syncthreads();
        v2f off = {0.0f, 0.0f};         // sg uniform per wave -> uniform branches
        #pragma unroll
        for (int s = 0; s < 7; ++s)
            if (sg > s) off += *(const v2f*)&S[s * LDW + 2 * c2];
        __syncthreads();                // offset reads done before overwrites

        float* sp = &S[r0 * LDW + 2 * c2];
        #pragma unroll
        for (int i = 0; i < 16; ++i) {  // 16x ds_write_b64, imm offsets
            v2f q = v[i] + off;
            *(v2f*)&sp[i * LDW] = q;
        }
    }
    __syncthreads();

    // ---- Phase B: cumsum over W. thread = (row, 32-col seg); quads share a row.
    {
        const int row = tid >> 2;       // wave = 16 rows x 4 col-segs
        const int ws_ = tid & 3;
        float* rp = &S[row * LDW + ws_ * 32];

        float u[32];
        #pragma unroll
        for (int i = 0; i < 8; ++i) {   // 8x ds_read_b128, imm offsets, conflict-free
            const float4 q = *(const float4*)&rp[i * 4];
            u[4 * i + 0] = q.x; u[4 * i + 1] = q.y;
            u[4 * i + 2] = q.z; u[4 * i + 3] = q.w;
        }
        #pragma unroll
        for (int i = 1; i < 32; ++i)
            u[i] += u[i - 1];

        const float tot = u[31];        // cross-seg fixup: 3 shuffles within quad
        const float t1 = __shfl_up(tot, 1, 64);
        const float t2 = __shfl_up(tot, 2, 64);
        const float t3 = __shfl_up(tot, 3, 64);
        float off = 0.0f;
        if (ws_ > 0) off += t1;
        if (ws_ > 1) off += t2;
        if (ws_ > 2) off += t3;

        #pragma unroll
        for (int i = 0; i < 8; ++i) {   // 8x ds_write_b128 in place
            float4 q;
            q.x = u[4 * i + 0] + off; q.y = u[4 * i + 1] + off;
            q.z = u[4 * i + 2] + off; q.w = u[4 * i + 3] + off;
            *(float4*)&rp[i * 4] = q;
        }
    }
    __syncthreads();

    // ---- Phase 3: pooling — thread n handles roi n for this channel ----
    {
        const int n = tid;              // 512 threads == 512 rois
        const float b_f = rois[n * 5 + 0];
        const int bi = (int)b_f;
        if (bi == b) {
            const float ss = 1.0f / (float)(*stride_p);
            const int d   = c / (GS * GS);
            const int rem = c - d * (GS * GS);
            const int pi  = rem / GS;
            const int pj  = rem - pi * GS;

            const float x1 = rois[n * 5 + 1];
            const float y1 = rois[n * 5 + 2];
            const float x2 = rois[n * 5 + 3];
            const float y2 = rois[n * 5 + 4];

            // exact reference op order, fp32, no contraction
            float rsw = rintf(x1) * ss;
            float rsh = rintf(y1) * ss;
            float rew = (rintf(x2) + 1.0f) * ss;
            float reh = (rintf(y2) + 1.0f) * ss;
            float rwv = rew - rsw;
            float rhv = reh - rsh;
            float rwm = rwv * 1.3f;
            float rhm = rhv * 1.3f;
            float swm = (rsw + rew) * 0.5f - rwm * 0.5f;
            float shm = (rsh + reh) * 0.5f - rhm * 0.5f;
            rwm = fmaxf(rwm, 0.1f);
            rhm = fmaxf(rhm, 0.1f);
            float bin_h = rhm / 7.0f;
            float bin_w = rwm / 7.0f;
            float dh = bin_h * 0.25f;
            float dw = bin_w * 0.25f;

            const float gi = (float)pi;
            const float gj = (float)pj;
            const int hs  = (int)fminf(fmaxf(floorf(shm + gi * bin_h - dh),          0.0f), 128.0f);
            const int he  = (int)fminf(fmaxf(ceilf (shm + (gi + 1.0f) * bin_h + dh), 0.0f), 128.0f);
            const int ws2 = (int)fminf(fmaxf(floorf(swm + gj * bin_w - dw),          0.0f), 128.0f);
            const int we  = (int)fminf(fmaxf(ceilf (swm + (gj + 1.0f) * bin_w + dw), 0.0f), 128.0f);

            const int area = (he - hs) * (we - ws2);
            const float A  = (he > 0 && we  > 0) ? S[(he - 1) * LDW + (we  - 1)] : 0.0f;
            const float Bv = (hs > 0 && we  > 0) ? S[(hs - 1) * LDW + (we  - 1)] : 0.0f;
            const float Cv = (he > 0 && ws2 > 0) ? S[(he - 1) * LDW + (ws2 - 1)] : 0.0f;
            const float Dv = (hs > 0 && ws2 > 0) ? S[(hs - 1) * LDW + (ws2 - 1)] : 0.0f;
            const float total = ((A - Bv) - Cv) + Dv;   // reference order
            out[(size_t)n * CCH + c] = (area > 0) ? (total / (float)area) : 0.0f;
        }
    }
}

extern "C" void kernel_launch(void* const* d_in, const int* in_sizes, int n_in,
                              void* d_out, int out_size, void* d_ws, size_t ws_size,
                              hipStream_t stream)
{
    const float* rois     = (const float*)d_in[0];
    const float* feat     = (const float*)d_in[1];
    const int*   stride_p = (const int*)d_in[2];
    float*       out      = (float*)d_out;

    dim3 grid(NB * CCH);   // one workgroup per (batch, channel)
    dim3 block(512);
    hipLaunchKernelGGL(psroi_fused, grid, block, 0, stream, rois, feat, stride_p, out);
}